// Round 1
// baseline (2081.149 us; speedup 1.0000x reference)
//
#include <hip/hip_runtime.h>
#include <hip/hip_bf16.h>
#include <cmath>

#define D_MODEL 768
#define D_INNER 1536
#define DT_RANK 48
#define D_STATE 16
#define D_CONV  4
#define BATCH   2
#define SEQ     2048
#define BL      (BATCH * SEQ)

__device__ __forceinline__ float siluf(float x) { return x / (1.f + __expf(-x)); }
__device__ __forceinline__ float softplusf(float x) {
    return (x > 20.f) ? x : log1pf(__expf(x));
}

// C[M,N] = A[M,K] @ Bw[N,K]^T   (both row-major; Bw is a weight matrix)
// EPI==1: C = softplus(C + bias[n])
template<int BM, int BN, int TM, int TN, int EPI>
__global__ __launch_bounds__(256) void gemm_nt(
    const float* __restrict__ A, const float* __restrict__ Bw,
    const float* __restrict__ bias, float* __restrict__ C,
    int M, int N, int K, int lda, int ldb, int ldc)
{
    constexpr int BK = 16;
    __shared__ float As[BK][BM + 4];
    __shared__ float Bs[BK][BN + 4];
    const int tid = threadIdx.x;
    const int bm0 = blockIdx.x * BM;
    const int bn0 = blockIdx.y * BN;
    constexpr int TX = BN / TN;                 // threads along N
    static_assert((BM / TM) * (BN / TN) == 256, "thread tile mismatch");
    const int tx = tid % TX;
    const int ty = tid / TX;
    const int row0 = ty * TM;
    const int col0 = tx * TN;
    float acc[TM][TN] = {};

    constexpr int A_PER = (BM * BK / 4) / 256;  // float4 loads per thread for A tile
    static_assert((BN * BK / 4) == 256, "B tile must be exactly 256 float4s");

    for (int k0 = 0; k0 < K; k0 += BK) {
#pragma unroll
        for (int i = 0; i < A_PER; ++i) {
            int idx = tid + i * 256;
            int r  = idx >> 2;
            int kq = (idx & 3) << 2;
            float4 v = make_float4(0.f, 0.f, 0.f, 0.f);
            int gr = bm0 + r;
            if (gr < M) v = *(const float4*)(A + (size_t)gr * lda + k0 + kq);
            As[kq + 0][r] = v.x; As[kq + 1][r] = v.y;
            As[kq + 2][r] = v.z; As[kq + 3][r] = v.w;
        }
        {
            int idx = tid;
            int r  = idx >> 2;
            int kq = (idx & 3) << 2;
            float4 v = make_float4(0.f, 0.f, 0.f, 0.f);
            int gr = bn0 + r;
            if (gr < N) v = *(const float4*)(Bw + (size_t)gr * ldb + k0 + kq);
            Bs[kq + 0][r] = v.x; Bs[kq + 1][r] = v.y;
            Bs[kq + 2][r] = v.z; Bs[kq + 3][r] = v.w;
        }
        __syncthreads();
#pragma unroll
        for (int k = 0; k < BK; ++k) {
            float a[TM], b[TN];
#pragma unroll
            for (int i = 0; i < TM; ++i) a[i] = As[k][row0 + i];
#pragma unroll
            for (int j = 0; j < TN; ++j) b[j] = Bs[k][col0 + j];
#pragma unroll
            for (int i = 0; i < TM; ++i)
#pragma unroll
                for (int j = 0; j < TN; ++j)
                    acc[i][j] = fmaf(a[i], b[j], acc[i][j]);
        }
        __syncthreads();
    }

#pragma unroll
    for (int i = 0; i < TM; ++i) {
        int r = bm0 + row0 + i;
        if (r >= M) continue;
#pragma unroll
        for (int j = 0; j < TN; ++j) {
            int c = bn0 + col0 + j;
            if (c >= N) continue;
            float v = acc[i][j];
            if (EPI == 1) { v += bias[c]; v = softplusf(v); }
            C[(size_t)r * ldc + c] = v;
        }
    }
}

// Causal depthwise conv (K=4) + bias + SiLU.
// Reads xs_raw = xr[:, 0:D_INNER] (row stride 2*D_INNER), writes xs (row stride D_INNER).
__global__ __launch_bounds__(256) void conv_silu_kernel(
    const float* __restrict__ xr, const float* __restrict__ Wc,
    const float* __restrict__ bc, float* __restrict__ xs)
{
    int idx = blockIdx.x * 256 + threadIdx.x;
    int d   = idx % D_INNER;
    int row = idx / D_INNER;      // b*SEQ + l
    int l   = row % SEQ;
    float w0 = Wc[d * 4 + 0], w1 = Wc[d * 4 + 1];
    float w2 = Wc[d * 4 + 2], w3 = Wc[d * 4 + 3];
    float acc = bc[d];
    const float* base = xr + (size_t)row * (2 * D_INNER) + d;
    const ptrdiff_t st = 2 * D_INNER;
    if (l >= 3) acc = fmaf(base[-3 * st], w0, acc);
    if (l >= 2) acc = fmaf(base[-2 * st], w1, acc);
    if (l >= 1) acc = fmaf(base[-1 * st], w2, acc);
    acc = fmaf(base[0], w3, acc);
    xs[idx] = siluf(acc);
}

// Selective scan. 16 lanes per (b,d) sequence, one state n per lane.
// delta comes from xr cols [0,D_INNER), res from xr cols [D_INNER, 2*D_INNER).
// Writes gated y in-place over xs.
__global__ __launch_bounds__(256) void scan_kernel(
    const float* __restrict__ xr,
    const float* __restrict__ xdbl,
    const float* __restrict__ A_log,
    const float* __restrict__ Dvec,
    float* __restrict__ xs_y)
{
    const int tid = threadIdx.x;
    const int n = tid & 15;
    const int g = blockIdx.x * 16 + (tid >> 4);   // (b,d) sequence index
    const int d = g % D_INNER;
    const int b = g / D_INNER;
    const float Acoef = -__expf(A_log[d * D_STATE + n]);
    const float Dd = Dvec[d];
    float h = 0.f;
    const float* dptr  = xr   + (size_t)b * SEQ * (2 * D_INNER) + d;
    const float* rptr  = dptr + D_INNER;
    const float* bcptr = xdbl + (size_t)b * SEQ * 80 + DT_RANK + n;
    float*       xptr  = xs_y + (size_t)b * SEQ * D_INNER + d;
    for (int l = 0; l < SEQ; ++l) {
        float dt = *dptr;
        float xt = *xptr;
        float Bv = bcptr[0];
        float Cv = bcptr[D_STATE];
        float dA = __expf(Acoef * dt);
        h = fmaf(dA, h, dt * xt * Bv);
        float p = h * Cv;
        p += __shfl_xor(p, 1);
        p += __shfl_xor(p, 2);
        p += __shfl_xor(p, 4);
        p += __shfl_xor(p, 8);
        if (n == 0) {
            float res = *rptr;
            *xptr = (p + xt * Dd) * siluf(res);
        }
        dptr += 2 * D_INNER; rptr += 2 * D_INNER; bcptr += 80; xptr += D_INNER;
    }
}

extern "C" void kernel_launch(void* const* d_in, const int* in_sizes, int n_in,
                              void* d_out, int out_size, void* d_ws, size_t ws_size,
                              hipStream_t stream) {
    const float* x      = (const float*)d_in[0];
    const float* W_in   = (const float*)d_in[1];
    const float* W_conv = (const float*)d_in[2];
    const float* b_conv = (const float*)d_in[3];
    const float* W_xproj= (const float*)d_in[4];
    const float* W_dt   = (const float*)d_in[5];
    const float* b_dt   = (const float*)d_in[6];
    const float* A_log  = (const float*)d_in[7];
    const float* Dv     = (const float*)d_in[8];
    const float* W_out  = (const float*)d_in[9];
    float* out = (float*)d_out;

    float* ws   = (float*)d_ws;
    float* xr   = ws;                               // BL * 3072  (x_and_res; later delta overwrites cols [0,1536))
    float* xs   = xr + (size_t)BL * 3072;           // BL * 1536  (xs post conv; scan overwrites with gated y)
    float* xdbl = xs + (size_t)BL * 1536;           // BL * 80

    dim3 blk(256);

    // 1) in_proj: xr = x @ W_in^T           (4096 x 3072, K=768)
    gemm_nt<128, 64, 8, 4, 0><<<dim3(BL / 128, 3072 / 64), blk, 0, stream>>>(
        x, W_in, nullptr, xr, BL, 2 * D_INNER, D_MODEL, D_MODEL, D_MODEL, 2 * D_INNER);

    // 2) causal depthwise conv + bias + SiLU -> xs
    conv_silu_kernel<<<dim3((BL * D_INNER) / 256), blk, 0, stream>>>(xr, W_conv, b_conv, xs);

    // 3) x_proj: xdbl = xs @ W_xproj^T      (4096 x 80, K=1536)
    gemm_nt<64, 64, 4, 4, 0><<<dim3(BL / 64, 2), blk, 0, stream>>>(
        xs, W_xproj, nullptr, xdbl, BL, DT_RANK + 2 * D_STATE, D_INNER, D_INNER, D_INNER, 80);

    // 4) delta = softplus(xdbl[:, :48] @ W_dt^T + b_dt) -> xr cols [0, 1536), ldc=3072
    gemm_nt<128, 64, 8, 4, 1><<<dim3(BL / 128, D_INNER / 64), blk, 0, stream>>>(
        xdbl, W_dt, b_dt, xr, BL, D_INNER, DT_RANK, 80, DT_RANK, 2 * D_INNER);

    // 5) selective scan + D-skip + gate, in-place on xs
    scan_kernel<<<dim3(BATCH * D_INNER / 16), blk, 0, stream>>>(xr, xdbl, A_log, Dv, xs);

    // 6) out_proj: out = y_gated @ W_out^T  (4096 x 768, K=1536)
    gemm_nt<128, 64, 8, 4, 0><<<dim3(BL / 128, D_MODEL / 64), blk, 0, stream>>>(
        xs, W_out, nullptr, out, BL, D_MODEL, D_INNER, D_INNER, D_INNER, D_MODEL);
}

// Round 2
// 809.066 us; speedup vs baseline: 2.5723x; 2.5723x over previous
//
#include <hip/hip_runtime.h>
#include <hip/hip_bf16.h>
#include <cmath>

#define D_MODEL 768
#define D_INNER 1536
#define DT_RANK 48
#define D_STATE 16
#define D_CONV  4
#define BATCH   2
#define SEQ     2048
#define BL      (BATCH * SEQ)
#define NSTATE_TOT (BATCH * D_INNER * D_STATE)   // 49152

__device__ __forceinline__ float siluf(float x) { return x / (1.f + __expf(-x)); }
__device__ __forceinline__ float softplusf(float x) {
    return (x > 20.f) ? x : log1pf(__expf(x));
}

// C[M,N] = A[M,K] @ Bw[N,K]^T   (both row-major; Bw is a weight matrix)
// EPI==1: C = softplus(C + bias[n])
template<int BM, int BN, int TM, int TN, int EPI>
__global__ __launch_bounds__(256) void gemm_nt(
    const float* __restrict__ A, const float* __restrict__ Bw,
    const float* __restrict__ bias, float* __restrict__ C,
    int M, int N, int K, int lda, int ldb, int ldc)
{
    constexpr int BK = 16;
    __shared__ float As[BK][BM + 4];
    __shared__ float Bs[BK][BN + 4];
    const int tid = threadIdx.x;
    const int bm0 = blockIdx.x * BM;
    const int bn0 = blockIdx.y * BN;
    constexpr int TX = BN / TN;
    static_assert((BM / TM) * (BN / TN) == 256, "thread tile mismatch");
    const int tx = tid % TX;
    const int ty = tid / TX;
    const int row0 = ty * TM;
    const int col0 = tx * TN;
    float acc[TM][TN] = {};

    constexpr int A_PER = (BM * BK / 4) / 256;
    static_assert((BN * BK / 4) == 256, "B tile must be exactly 256 float4s");

    for (int k0 = 0; k0 < K; k0 += BK) {
#pragma unroll
        for (int i = 0; i < A_PER; ++i) {
            int idx = tid + i * 256;
            int r  = idx >> 2;
            int kq = (idx & 3) << 2;
            float4 v = make_float4(0.f, 0.f, 0.f, 0.f);
            int gr = bm0 + r;
            if (gr < M) v = *(const float4*)(A + (size_t)gr * lda + k0 + kq);
            As[kq + 0][r] = v.x; As[kq + 1][r] = v.y;
            As[kq + 2][r] = v.z; As[kq + 3][r] = v.w;
        }
        {
            int idx = tid;
            int r  = idx >> 2;
            int kq = (idx & 3) << 2;
            float4 v = make_float4(0.f, 0.f, 0.f, 0.f);
            int gr = bn0 + r;
            if (gr < N) v = *(const float4*)(Bw + (size_t)gr * ldb + k0 + kq);
            Bs[kq + 0][r] = v.x; Bs[kq + 1][r] = v.y;
            Bs[kq + 2][r] = v.z; Bs[kq + 3][r] = v.w;
        }
        __syncthreads();
#pragma unroll
        for (int k = 0; k < BK; ++k) {
            float a[TM], b[TN];
#pragma unroll
            for (int i = 0; i < TM; ++i) a[i] = As[k][row0 + i];
#pragma unroll
            for (int j = 0; j < TN; ++j) b[j] = Bs[k][col0 + j];
#pragma unroll
            for (int i = 0; i < TM; ++i)
#pragma unroll
                for (int j = 0; j < TN; ++j)
                    acc[i][j] = fmaf(a[i], b[j], acc[i][j]);
        }
        __syncthreads();
    }

#pragma unroll
    for (int i = 0; i < TM; ++i) {
        int r = bm0 + row0 + i;
        if (r >= M) continue;
#pragma unroll
        for (int j = 0; j < TN; ++j) {
            int c = bn0 + col0 + j;
            if (c >= N) continue;
            float v = acc[i][j];
            if (EPI == 1) { v += bias[c]; v = softplusf(v); }
            C[(size_t)r * ldc + c] = v;
        }
    }
}

// Causal depthwise conv (K=4) + bias + SiLU.
__global__ __launch_bounds__(256) void conv_silu_kernel(
    const float* __restrict__ xr, const float* __restrict__ Wc,
    const float* __restrict__ bc, float* __restrict__ xs)
{
    int idx = blockIdx.x * 256 + threadIdx.x;
    int d   = idx % D_INNER;
    int row = idx / D_INNER;      // b*SEQ + l
    int l   = row % SEQ;
    float w0 = Wc[d * 4 + 0], w1 = Wc[d * 4 + 1];
    float w2 = Wc[d * 4 + 2], w3 = Wc[d * 4 + 3];
    float acc = bc[d];
    const float* base = xr + (size_t)row * (2 * D_INNER) + d;
    const ptrdiff_t st = 2 * D_INNER;
    if (l >= 3) acc = fmaf(base[-3 * st], w0, acc);
    if (l >= 2) acc = fmaf(base[-2 * st], w1, acc);
    if (l >= 1) acc = fmaf(base[-1 * st], w2, acc);
    acc = fmaf(base[0], w3, acc);
    xs[idx] = siluf(acc);
}

// ---- Chunked parallel scan ----
// Group g encodes (c,b,d) as g = (c*BATCH + b)*D_INNER + d; lane n = tid&15.
// Storage layout for P/S/Hin: flat [c][b][d][n] == g*16 + n (coalesced both passes).

// Pass A: per chunk, local scan from h=0 -> S, and P = exp(Acoef * sum dt).
__global__ __launch_bounds__(256) void scan_part1(
    const float* __restrict__ xr, const float* __restrict__ xs,
    const float* __restrict__ xdbl, const float* __restrict__ A_log,
    float* __restrict__ P, float* __restrict__ S, int CL)
{
    const int tid = threadIdx.x;
    const int n = tid & 15;
    const int g = blockIdx.x * 16 + (tid >> 4);
    const int d = g % D_INNER;
    const int cb = g / D_INNER;
    const int b = cb % BATCH;
    const int c = cb / BATCH;
    const int l0 = c * CL;
    const float Acoef = -__expf(A_log[d * D_STATE + n]);
    float h = 0.f, sdt = 0.f;
    const float* dptr = xr   + ((size_t)b * SEQ + l0) * (2 * D_INNER) + d;
    const float* xptr = xs   + ((size_t)b * SEQ + l0) * D_INNER + d;
    const float* bptr = xdbl + ((size_t)b * SEQ + l0) * 80 + DT_RANK + n;
#pragma unroll 4
    for (int l = 0; l < CL; ++l) {
        float dt = *dptr;
        float xt = *xptr;
        float Bv = *bptr;
        float dA = __expf(Acoef * dt);
        h = fmaf(dA, h, dt * xt * Bv);
        sdt += dt;
        dptr += 2 * D_INNER; xptr += D_INNER; bptr += 80;
    }
    P[(size_t)g * D_STATE + n] = __expf(Acoef * sdt);
    S[(size_t)g * D_STATE + n] = h;
}

// Pass B: sequential combine over chunks; writes the INCOMING state per chunk.
__global__ __launch_bounds__(256) void scan_combine(
    const float* __restrict__ P, const float* __restrict__ S,
    float* __restrict__ Hin, int NC)
{
    const int j = blockIdx.x * 256 + threadIdx.x;   // < NSTATE_TOT
    float h = 0.f;
    for (int c = 0; c < NC; ++c) {
        size_t idx = (size_t)c * NSTATE_TOT + j;
        Hin[idx] = h;
        h = fmaf(P[idx], h, S[idx]);
    }
}

// Pass C: re-scan each chunk from Hin, reduce over n, D-skip + gate, write y in place.
__global__ __launch_bounds__(256) void scan_part2(
    const float* __restrict__ xr, const float* __restrict__ xdbl,
    const float* __restrict__ A_log, const float* __restrict__ Dvec,
    const float* __restrict__ Hin, float* __restrict__ xs_y, int CL)
{
    const int tid = threadIdx.x;
    const int n = tid & 15;
    const int g = blockIdx.x * 16 + (tid >> 4);
    const int d = g % D_INNER;
    const int cb = g / D_INNER;
    const int b = cb % BATCH;
    const int c = cb / BATCH;
    const int l0 = c * CL;
    const float Acoef = -__expf(A_log[d * D_STATE + n]);
    const float Dd = Dvec[d];
    float h = Hin ? Hin[(size_t)g * D_STATE + n] : 0.f;
    const float* dptr  = xr   + ((size_t)b * SEQ + l0) * (2 * D_INNER) + d;
    const float* rptr  = dptr + D_INNER;
    const float* bcptr = xdbl + ((size_t)b * SEQ + l0) * 80 + DT_RANK + n;
    float*       xptr  = xs_y + ((size_t)b * SEQ + l0) * D_INNER + d;
    for (int l = 0; l < CL; ++l) {
        float dt = *dptr;
        float xt = *xptr;
        float Bv = bcptr[0];
        float Cv = bcptr[D_STATE];
        float dA = __expf(Acoef * dt);
        h = fmaf(dA, h, dt * xt * Bv);
        float p = h * Cv;
        p += __shfl_xor(p, 1);
        p += __shfl_xor(p, 2);
        p += __shfl_xor(p, 4);
        p += __shfl_xor(p, 8);
        if (n == 0) {
            *xptr = (p + xt * Dd) * siluf(*rptr);
        }
        dptr += 2 * D_INNER; rptr += 2 * D_INNER; bcptr += 80; xptr += D_INNER;
    }
}

extern "C" void kernel_launch(void* const* d_in, const int* in_sizes, int n_in,
                              void* d_out, int out_size, void* d_ws, size_t ws_size,
                              hipStream_t stream) {
    const float* x      = (const float*)d_in[0];
    const float* W_in   = (const float*)d_in[1];
    const float* W_conv = (const float*)d_in[2];
    const float* b_conv = (const float*)d_in[3];
    const float* W_xproj= (const float*)d_in[4];
    const float* W_dt   = (const float*)d_in[5];
    const float* b_dt   = (const float*)d_in[6];
    const float* A_log  = (const float*)d_in[7];
    const float* Dv     = (const float*)d_in[8];
    const float* W_out  = (const float*)d_in[9];
    float* out = (float*)d_out;

    float* ws   = (float*)d_ws;
    float* xr   = ws;                               // BL * 3072
    float* xs   = xr + (size_t)BL * 3072;           // BL * 1536
    float* xdbl = xs + (size_t)BL * 1536;           // BL * 80
    float* scr  = xdbl + (size_t)BL * 80;           // scan scratch: P, S, Hin

    // Pick the largest chunk count whose P/S/Hin scratch fits in d_ws.
    size_t fixed_bytes = ((size_t)BL * 3072 + (size_t)BL * 1536 + (size_t)BL * 80) * 4;
    int NC = 0;
    for (int cand = 32; cand >= 2; cand >>= 1) {
        size_t need = fixed_bytes + 3ull * cand * NSTATE_TOT * 4;
        if (need <= ws_size) { NC = cand; break; }
    }

    dim3 blk(256);

    // 1) in_proj: xr = x @ W_in^T           (4096 x 3072, K=768)
    gemm_nt<128, 64, 8, 4, 0><<<dim3(BL / 128, 3072 / 64), blk, 0, stream>>>(
        x, W_in, nullptr, xr, BL, 2 * D_INNER, D_MODEL, D_MODEL, D_MODEL, 2 * D_INNER);

    // 2) causal depthwise conv + bias + SiLU -> xs
    conv_silu_kernel<<<dim3((BL * D_INNER) / 256), blk, 0, stream>>>(xr, W_conv, b_conv, xs);

    // 3) x_proj: xdbl = xs @ W_xproj^T      (4096 x 80, K=1536)
    gemm_nt<64, 64, 4, 4, 0><<<dim3(BL / 64, 2), blk, 0, stream>>>(
        xs, W_xproj, nullptr, xdbl, BL, DT_RANK + 2 * D_STATE, D_INNER, D_INNER, D_INNER, 80);

    // 4) delta = softplus(xdbl[:, :48] @ W_dt^T + b_dt) -> xr cols [0,1536), ldc=3072
    gemm_nt<128, 64, 8, 4, 1><<<dim3(BL / 128, D_INNER / 64), blk, 0, stream>>>(
        xdbl, W_dt, b_dt, xr, BL, D_INNER, DT_RANK, 80, DT_RANK, 2 * D_INNER);

    // 5) chunked selective scan + D-skip + gate, in-place on xs
    if (NC >= 2) {
        const int CL = SEQ / NC;
        float* P   = scr;
        float* S   = P + (size_t)NC * NSTATE_TOT;
        float* Hin = S + (size_t)NC * NSTATE_TOT;
        scan_part1<<<dim3(NC * BATCH * D_INNER / 16), blk, 0, stream>>>(
            xr, xs, xdbl, A_log, P, S, CL);
        scan_combine<<<dim3(NSTATE_TOT / 256), blk, 0, stream>>>(P, S, Hin, NC);
        scan_part2<<<dim3(NC * BATCH * D_INNER / 16), blk, 0, stream>>>(
            xr, xdbl, A_log, Dv, Hin, xs, CL);
    } else {
        scan_part2<<<dim3(BATCH * D_INNER / 16), blk, 0, stream>>>(
            xr, xdbl, A_log, Dv, nullptr, xs, SEQ);
    }

    // 6) out_proj: out = y_gated @ W_out^T  (4096 x 768, K=1536)
    gemm_nt<128, 64, 8, 4, 0><<<dim3(BL / 128, D_MODEL / 64), blk, 0, stream>>>(
        xs, W_out, nullptr, out, BL, D_MODEL, D_INNER, D_INNER, D_INNER, D_MODEL);
}

// Round 3
// 565.896 us; speedup vs baseline: 3.6776x; 1.4297x over previous
//
#include <hip/hip_runtime.h>
#include <hip/hip_bf16.h>
#include <cmath>

#define D_MODEL 768
#define D_INNER 1536
#define DT_RANK 48
#define D_STATE 16
#define D_CONV  4
#define BATCH   2
#define SEQ     2048
#define BL      (BATCH * SEQ)
#define NSTATE_TOT (BATCH * D_INNER * D_STATE)   // 49152

typedef __attribute__((ext_vector_type(8))) __bf16 bf16x8;
typedef __attribute__((ext_vector_type(8))) short short8;
typedef __attribute__((ext_vector_type(4))) float f32x4;

__device__ __forceinline__ float siluf(float x) { return x / (1.f + __expf(-x)); }
__device__ __forceinline__ float softplusf(float x) {
    return (x > 20.f) ? x : log1pf(__expf(x));
}

// fp32 -> (hi, lo) bf16 pair, RNE. x ≈ hi + lo with ~2^-17 relative residual.
__device__ __forceinline__ void split2(float x, short& hi, short& lo) {
    unsigned u = __float_as_uint(x);
    unsigned r = (u + 0x7fff + ((u >> 16) & 1)) >> 16;
    hi = (short)r;
    float fh = __uint_as_float(r << 16);
    float l = x - fh;
    unsigned u2 = __float_as_uint(l);
    lo = (short)((u2 + 0x7fff + ((u2 >> 16) & 1)) >> 16);
}

// Stage a [R rows x 32 k] fp32 tile as split hi/lo bf16 into LDS (stride 40 bf16).
// Zero-fills k-groups beyond K. src is already offset to the tile's first row.
template<int R>
__device__ __forceinline__ void stage_tile(
    const float* __restrict__ src, int ld, int k0, int K,
    short* sh, short* sl, int tid)
{
    constexpr int G = R * 4;                 // groups of 8 floats
    for (int gi = tid; gi < G; gi += 256) {
        int row = gi >> 2;
        int k8  = (gi & 3) << 3;
        float xv[8];
        if (k0 + k8 + 8 <= K) {
            const float* p = src + (size_t)row * ld + k0 + k8;
            float4 v0 = ((const float4*)p)[0];
            float4 v1 = ((const float4*)p)[1];
            xv[0]=v0.x; xv[1]=v0.y; xv[2]=v0.z; xv[3]=v0.w;
            xv[4]=v1.x; xv[5]=v1.y; xv[6]=v1.z; xv[7]=v1.w;
        } else {
#pragma unroll
            for (int e = 0; e < 8; ++e) xv[e] = 0.f;
        }
        short h[8], l[8];
#pragma unroll
        for (int e = 0; e < 8; ++e) split2(xv[e], h[e], l[e]);
        int off = row * 40 + k8;
        short8 vh, vl;
#pragma unroll
        for (int e = 0; e < 8; ++e) { vh[e] = h[e]; vl[e] = l[e]; }
        *(short8*)(sh + off) = vh;
        *(short8*)(sl + off) = vl;
    }
}

// C[M,N] = A[M,K] @ Bw[N,K]^T via split-bf16 MFMA (3-term emulation).
// EPI==1: C = softplus(C + bias[n]).  M must divide BM; N covered by gridDim.y*BN.
template<int BM, int BN, int WM, int WN, int EPI>
__global__ __launch_bounds__(256) void gemm_mfma(
    const float* __restrict__ A, const float* __restrict__ Bw,
    const float* __restrict__ bias, float* __restrict__ C,
    int M, int N, int K, int lda, int ldb, int ldc)
{
    constexpr int NWM = BM / WM;
    constexpr int NWN = BN / WN;
    static_assert(NWM * NWN == 4, "4 waves");
    constexpr int FM = WM / 16;
    constexpr int FN = WN / 16;

    __shared__ short Ah[BM * 40], Al[BM * 40];
    __shared__ short Bh[BN * 40], Bl[BN * 40];

    const int tid  = threadIdx.x;
    const int lane = tid & 63;
    const int wid  = tid >> 6;
    const int bm0  = blockIdx.x * BM;
    const int bn0  = blockIdx.y * BN;
    const int wm0  = (wid / NWN) * WM;
    const int wn0  = (wid % NWN) * WN;

    f32x4 acc[FM][FN];
#pragma unroll
    for (int i = 0; i < FM; ++i)
#pragma unroll
        for (int j = 0; j < FN; ++j)
            acc[i][j] = (f32x4){0.f, 0.f, 0.f, 0.f};

    const float* Atile = A + (size_t)bm0 * lda;
    const float* Btile = Bw + (size_t)bn0 * ldb;
    const int rsel = lane & 15;          // row (A) / col (B) selector
    const int ksel = (lane >> 4) * 8;    // k-slot element offset

    for (int k0 = 0; k0 < K; k0 += 32) {
        stage_tile<BM>(Atile, lda, k0, K, Ah, Al, tid);
        stage_tile<BN>(Btile, ldb, k0, K, Bh, Bl, tid);
        __syncthreads();

        bf16x8 afh[FM], afl[FM], bfh[FN], bfl[FN];
#pragma unroll
        for (int i = 0; i < FM; ++i) {
            int off = (wm0 + i * 16 + rsel) * 40 + ksel;
            afh[i] = *(const bf16x8*)(Ah + off);
            afl[i] = *(const bf16x8*)(Al + off);
        }
#pragma unroll
        for (int j = 0; j < FN; ++j) {
            int off = (wn0 + j * 16 + rsel) * 40 + ksel;
            bfh[j] = *(const bf16x8*)(Bh + off);
            bfl[j] = *(const bf16x8*)(Bl + off);
        }
#pragma unroll
        for (int i = 0; i < FM; ++i)
#pragma unroll
            for (int j = 0; j < FN; ++j) {
                acc[i][j] = __builtin_amdgcn_mfma_f32_16x16x32_bf16(afl[i], bfh[j], acc[i][j], 0, 0, 0);
                acc[i][j] = __builtin_amdgcn_mfma_f32_16x16x32_bf16(afh[i], bfl[j], acc[i][j], 0, 0, 0);
                acc[i][j] = __builtin_amdgcn_mfma_f32_16x16x32_bf16(afh[i], bfh[j], acc[i][j], 0, 0, 0);
            }
        __syncthreads();
    }

    const int r0 = bm0 + wm0 + (lane >> 4) * 4;
    const int c0 = bn0 + wn0 + rsel;
#pragma unroll
    for (int i = 0; i < FM; ++i)
#pragma unroll
        for (int j = 0; j < FN; ++j) {
            int c = c0 + j * 16;
            if (c >= N) continue;
#pragma unroll
            for (int q = 0; q < 4; ++q) {
                int r = r0 + i * 16 + q;
                float v = acc[i][j][q];
                if (EPI == 1) { v += bias[c]; v = softplusf(v); }
                C[(size_t)r * ldc + c] = v;
            }
        }
}

// Causal depthwise conv (K=4) + bias + SiLU.
__global__ __launch_bounds__(256) void conv_silu_kernel(
    const float* __restrict__ xr, const float* __restrict__ Wc,
    const float* __restrict__ bc, float* __restrict__ xs)
{
    int idx = blockIdx.x * 256 + threadIdx.x;
    int d   = idx % D_INNER;
    int row = idx / D_INNER;      // b*SEQ + l
    int l   = row % SEQ;
    float w0 = Wc[d * 4 + 0], w1 = Wc[d * 4 + 1];
    float w2 = Wc[d * 4 + 2], w3 = Wc[d * 4 + 3];
    float acc = bc[d];
    const float* base = xr + (size_t)row * (2 * D_INNER) + d;
    const ptrdiff_t st = 2 * D_INNER;
    if (l >= 3) acc = fmaf(base[-3 * st], w0, acc);
    if (l >= 2) acc = fmaf(base[-2 * st], w1, acc);
    if (l >= 1) acc = fmaf(base[-1 * st], w2, acc);
    acc = fmaf(base[0], w3, acc);
    xs[idx] = siluf(acc);
}

// ---- Chunked parallel scan (g = (c*BATCH+b)*D_INNER + d, lane n = tid&15) ----

__global__ __launch_bounds__(256) void scan_part1(
    const float* __restrict__ xr, const float* __restrict__ xs,
    const float* __restrict__ xdbl, const float* __restrict__ A_log,
    float* __restrict__ P, float* __restrict__ S, int CL)
{
    const int tid = threadIdx.x;
    const int n = tid & 15;
    const int g = blockIdx.x * 16 + (tid >> 4);
    const int d = g % D_INNER;
    const int cb = g / D_INNER;
    const int b = cb % BATCH;
    const int c = cb / BATCH;
    const int l0 = c * CL;
    const float Acoef = -__expf(A_log[d * D_STATE + n]);
    float h = 0.f, sdt = 0.f;
    const float* dptr = xr   + ((size_t)b * SEQ + l0) * (2 * D_INNER) + d;
    const float* xptr = xs   + ((size_t)b * SEQ + l0) * D_INNER + d;
    const float* bptr = xdbl + ((size_t)b * SEQ + l0) * 80 + DT_RANK + n;
#pragma unroll 4
    for (int l = 0; l < CL; ++l) {
        float dt = *dptr;
        float xt = *xptr;
        float Bv = *bptr;
        float dA = __expf(Acoef * dt);
        h = fmaf(dA, h, dt * xt * Bv);
        sdt += dt;
        dptr += 2 * D_INNER; xptr += D_INNER; bptr += 80;
    }
    P[(size_t)g * D_STATE + n] = __expf(Acoef * sdt);
    S[(size_t)g * D_STATE + n] = h;
}

__global__ __launch_bounds__(256) void scan_combine(
    const float* __restrict__ P, const float* __restrict__ S,
    float* __restrict__ Hin, int NC)
{
    const int j = blockIdx.x * 256 + threadIdx.x;   // < NSTATE_TOT
    float h = 0.f;
    for (int c = 0; c < NC; ++c) {
        size_t idx = (size_t)c * NSTATE_TOT + j;
        Hin[idx] = h;
        h = fmaf(P[idx], h, S[idx]);
    }
}

__global__ __launch_bounds__(256) void scan_part2(
    const float* __restrict__ xr, const float* __restrict__ xdbl,
    const float* __restrict__ A_log, const float* __restrict__ Dvec,
    const float* __restrict__ Hin, float* __restrict__ xs_y, int CL)
{
    const int tid = threadIdx.x;
    const int n = tid & 15;
    const int g = blockIdx.x * 16 + (tid >> 4);
    const int d = g % D_INNER;
    const int cb = g / D_INNER;
    const int b = cb % BATCH;
    const int c = cb / BATCH;
    const int l0 = c * CL;
    const float Acoef = -__expf(A_log[d * D_STATE + n]);
    const float Dd = Dvec[d];
    float h = Hin ? Hin[(size_t)g * D_STATE + n] : 0.f;
    const float* dptr  = xr   + ((size_t)b * SEQ + l0) * (2 * D_INNER) + d;
    const float* rptr  = dptr + D_INNER;
    const float* bcptr = xdbl + ((size_t)b * SEQ + l0) * 80 + DT_RANK + n;
    float*       xptr  = xs_y + ((size_t)b * SEQ + l0) * D_INNER + d;
    for (int l = 0; l < CL; ++l) {
        float dt = *dptr;
        float xt = *xptr;
        float Bv = bcptr[0];
        float Cv = bcptr[D_STATE];
        float dA = __expf(Acoef * dt);
        h = fmaf(dA, h, dt * xt * Bv);
        float p = h * Cv;
        p += __shfl_xor(p, 1);
        p += __shfl_xor(p, 2);
        p += __shfl_xor(p, 4);
        p += __shfl_xor(p, 8);
        if (n == 0) {
            *xptr = (p + xt * Dd) * siluf(*rptr);
        }
        dptr += 2 * D_INNER; rptr += 2 * D_INNER; bcptr += 80; xptr += D_INNER;
    }
}

extern "C" void kernel_launch(void* const* d_in, const int* in_sizes, int n_in,
                              void* d_out, int out_size, void* d_ws, size_t ws_size,
                              hipStream_t stream) {
    const float* x      = (const float*)d_in[0];
    const float* W_in   = (const float*)d_in[1];
    const float* W_conv = (const float*)d_in[2];
    const float* b_conv = (const float*)d_in[3];
    const float* W_xproj= (const float*)d_in[4];
    const float* W_dt   = (const float*)d_in[5];
    const float* b_dt   = (const float*)d_in[6];
    const float* A_log  = (const float*)d_in[7];
    const float* Dv     = (const float*)d_in[8];
    const float* W_out  = (const float*)d_in[9];
    float* out = (float*)d_out;

    float* ws   = (float*)d_ws;
    float* xr   = ws;                               // BL * 3072
    float* xs   = xr + (size_t)BL * 3072;           // BL * 1536
    float* xdbl = xs + (size_t)BL * 1536;           // BL * 80
    float* scr  = xdbl + (size_t)BL * 80;           // scan scratch: P, S, Hin

    size_t fixed_bytes = ((size_t)BL * 3072 + (size_t)BL * 1536 + (size_t)BL * 80) * 4;
    int NC = 0;
    for (int cand = 32; cand >= 2; cand >>= 1) {
        size_t need = fixed_bytes + 3ull * cand * NSTATE_TOT * 4;
        if (need <= ws_size) { NC = cand; break; }
    }

    dim3 blk(256);

    // 1) in_proj: xr = x @ W_in^T           (4096 x 3072, K=768)
    gemm_mfma<128, 128, 64, 64, 0><<<dim3(BL / 128, 3072 / 128), blk, 0, stream>>>(
        x, W_in, nullptr, xr, BL, 2 * D_INNER, D_MODEL, D_MODEL, D_MODEL, 2 * D_INNER);

    // 2) causal depthwise conv + bias + SiLU -> xs
    conv_silu_kernel<<<dim3((BL * D_INNER) / 256), blk, 0, stream>>>(xr, W_conv, b_conv, xs);

    // 3) x_proj: xdbl = xs @ W_xproj^T      (4096 x 80, K=1536)
    gemm_mfma<64, 80, 16, 80, 0><<<dim3(BL / 64, 1), blk, 0, stream>>>(
        xs, W_xproj, nullptr, xdbl, BL, DT_RANK + 2 * D_STATE, D_INNER, D_INNER, D_INNER, 80);

    // 4) delta = softplus(xdbl[:, :48] @ W_dt^T + b_dt) -> xr cols [0,1536), ldc=3072
    gemm_mfma<128, 128, 64, 64, 1><<<dim3(BL / 128, D_INNER / 128), blk, 0, stream>>>(
        xdbl, W_dt, b_dt, xr, BL, D_INNER, DT_RANK, 80, DT_RANK, 2 * D_INNER);

    // 5) chunked selective scan + D-skip + gate, in-place on xs
    if (NC >= 2) {
        const int CL = SEQ / NC;
        float* P   = scr;
        float* S   = P + (size_t)NC * NSTATE_TOT;
        float* Hin = S + (size_t)NC * NSTATE_TOT;
        scan_part1<<<dim3(NC * BATCH * D_INNER / 16), blk, 0, stream>>>(
            xr, xs, xdbl, A_log, P, S, CL);
        scan_combine<<<dim3(NSTATE_TOT / 256), blk, 0, stream>>>(P, S, Hin, NC);
        scan_part2<<<dim3(NC * BATCH * D_INNER / 16), blk, 0, stream>>>(
            xr, xdbl, A_log, Dv, Hin, xs, CL);
    } else {
        scan_part2<<<dim3(BATCH * D_INNER / 16), blk, 0, stream>>>(
            xr, xdbl, A_log, Dv, nullptr, xs, SEQ);
    }

    // 6) out_proj: out = y_gated @ W_out^T  (4096 x 768, K=1536)
    gemm_mfma<128, 128, 64, 64, 0><<<dim3(BL / 128, D_MODEL / 128), blk, 0, stream>>>(
        xs, W_out, nullptr, out, BL, D_MODEL, D_INNER, D_INNER, D_INNER, D_MODEL);
}

// Round 4
// 445.499 us; speedup vs baseline: 4.6715x; 1.2703x over previous
//
#include <hip/hip_runtime.h>
#include <hip/hip_bf16.h>
#include <cmath>

#define D_MODEL 768
#define D_INNER 1536
#define DT_RANK 48
#define D_STATE 16
#define D_CONV  4
#define BATCH   2
#define SEQ     2048
#define BL      (BATCH * SEQ)
#define NSTATE_TOT (BATCH * D_INNER * D_STATE)   // 49152

typedef __attribute__((ext_vector_type(8))) __bf16 bf16x8;
typedef __attribute__((ext_vector_type(8))) short short8;
typedef __attribute__((ext_vector_type(4))) float f32x4;

__device__ __forceinline__ float siluf(float x) { return x / (1.f + __expf(-x)); }
__device__ __forceinline__ float softplusf(float x) {
    return (x > 20.f) ? x : log1pf(__expf(x));
}

// fp32 -> (hi, lo) bf16 pair, RNE.
__device__ __forceinline__ void split2(float x, short& hi, short& lo) {
    unsigned u = __float_as_uint(x);
    unsigned r = (u + 0x7fff + ((u >> 16) & 1)) >> 16;
    hi = (short)r;
    float fh = __uint_as_float(r << 16);
    float l = x - fh;
    unsigned u2 = __float_as_uint(l);
    lo = (short)((u2 + 0x7fff + ((u2 >> 16) & 1)) >> 16);
}

template<int R>
__device__ __forceinline__ void stage_tile(
    const float* __restrict__ src, int ld, int k0, int K,
    short* sh, short* sl, int tid)
{
    constexpr int G = R * 4;
    for (int gi = tid; gi < G; gi += 256) {
        int row = gi >> 2;
        int k8  = (gi & 3) << 3;
        float xv[8];
        if (k0 + k8 + 8 <= K) {
            const float* p = src + (size_t)row * ld + k0 + k8;
            float4 v0 = ((const float4*)p)[0];
            float4 v1 = ((const float4*)p)[1];
            xv[0]=v0.x; xv[1]=v0.y; xv[2]=v0.z; xv[3]=v0.w;
            xv[4]=v1.x; xv[5]=v1.y; xv[6]=v1.z; xv[7]=v1.w;
        } else {
#pragma unroll
            for (int e = 0; e < 8; ++e) xv[e] = 0.f;
        }
        short h[8], l[8];
#pragma unroll
        for (int e = 0; e < 8; ++e) split2(xv[e], h[e], l[e]);
        int off = row * 40 + k8;
        short8 vh, vl;
#pragma unroll
        for (int e = 0; e < 8; ++e) { vh[e] = h[e]; vl[e] = l[e]; }
        *(short8*)(sh + off) = vh;
        *(short8*)(sl + off) = vl;
    }
}

// C[M,N] = A[M,K] @ Bw[N,K]^T via split-bf16 MFMA (3-term emulation).
template<int BM, int BN, int WM, int WN, int EPI>
__global__ __launch_bounds__(256) void gemm_mfma(
    const float* __restrict__ A, const float* __restrict__ Bw,
    const float* __restrict__ bias, float* __restrict__ C,
    int M, int N, int K, int lda, int ldb, int ldc)
{
    constexpr int NWM = BM / WM;
    constexpr int NWN = BN / WN;
    static_assert(NWM * NWN == 4, "4 waves");
    constexpr int FM = WM / 16;
    constexpr int FN = WN / 16;

    __shared__ short Ah[BM * 40], Al[BM * 40];
    __shared__ short Bh[BN * 40], Bl[BN * 40];

    const int tid  = threadIdx.x;
    const int lane = tid & 63;
    const int wid  = tid >> 6;
    const int bm0  = blockIdx.x * BM;
    const int bn0  = blockIdx.y * BN;
    const int wm0  = (wid / NWN) * WM;
    const int wn0  = (wid % NWN) * WN;

    f32x4 acc[FM][FN];
#pragma unroll
    for (int i = 0; i < FM; ++i)
#pragma unroll
        for (int j = 0; j < FN; ++j)
            acc[i][j] = (f32x4){0.f, 0.f, 0.f, 0.f};

    const float* Atile = A + (size_t)bm0 * lda;
    const float* Btile = Bw + (size_t)bn0 * ldb;
    const int rsel = lane & 15;
    const int ksel = (lane >> 4) * 8;

    for (int k0 = 0; k0 < K; k0 += 32) {
        stage_tile<BM>(Atile, lda, k0, K, Ah, Al, tid);
        stage_tile<BN>(Btile, ldb, k0, K, Bh, Bl, tid);
        __syncthreads();

        bf16x8 afh[FM], afl[FM], bfh[FN], bfl[FN];
#pragma unroll
        for (int i = 0; i < FM; ++i) {
            int off = (wm0 + i * 16 + rsel) * 40 + ksel;
            afh[i] = *(const bf16x8*)(Ah + off);
            afl[i] = *(const bf16x8*)(Al + off);
        }
#pragma unroll
        for (int j = 0; j < FN; ++j) {
            int off = (wn0 + j * 16 + rsel) * 40 + ksel;
            bfh[j] = *(const bf16x8*)(Bh + off);
            bfl[j] = *(const bf16x8*)(Bl + off);
        }
#pragma unroll
        for (int i = 0; i < FM; ++i)
#pragma unroll
            for (int j = 0; j < FN; ++j) {
                acc[i][j] = __builtin_amdgcn_mfma_f32_16x16x32_bf16(afl[i], bfh[j], acc[i][j], 0, 0, 0);
                acc[i][j] = __builtin_amdgcn_mfma_f32_16x16x32_bf16(afh[i], bfl[j], acc[i][j], 0, 0, 0);
                acc[i][j] = __builtin_amdgcn_mfma_f32_16x16x32_bf16(afh[i], bfh[j], acc[i][j], 0, 0, 0);
            }
        __syncthreads();
    }

    const int r0 = bm0 + wm0 + (lane >> 4) * 4;
    const int c0 = bn0 + wn0 + rsel;
#pragma unroll
    for (int i = 0; i < FM; ++i)
#pragma unroll
        for (int j = 0; j < FN; ++j) {
            int c = c0 + j * 16;
            if (c >= N) continue;
#pragma unroll
            for (int q = 0; q < 4; ++q) {
                int r = r0 + i * 16 + q;
                float v = acc[i][j][q];
                if (EPI == 1) { v += bias[c]; v = softplusf(v); }
                C[(size_t)r * ldc + c] = v;
            }
        }
}

// Causal depthwise conv (K=4) + bias + SiLU.
__global__ __launch_bounds__(256) void conv_silu_kernel(
    const float* __restrict__ xr, const float* __restrict__ Wc,
    const float* __restrict__ bc, float* __restrict__ xs)
{
    int idx = blockIdx.x * 256 + threadIdx.x;
    int d   = idx % D_INNER;
    int row = idx / D_INNER;
    int l   = row % SEQ;
    float w0 = Wc[d * 4 + 0], w1 = Wc[d * 4 + 1];
    float w2 = Wc[d * 4 + 2], w3 = Wc[d * 4 + 3];
    float acc = bc[d];
    const float* base = xr + (size_t)row * (2 * D_INNER) + d;
    const ptrdiff_t st = 2 * D_INNER;
    if (l >= 3) acc = fmaf(base[-3 * st], w0, acc);
    if (l >= 2) acc = fmaf(base[-2 * st], w1, acc);
    if (l >= 1) acc = fmaf(base[-1 * st], w2, acc);
    acc = fmaf(base[0], w3, acc);
    xs[idx] = siluf(acc);
}

// ---- Chunked parallel scan, 16 states per THREAD ----
// Thread t = (c*BATCH + b)*D_INNER + d. P/S/Hin layout: flat [c][b][d][n] = t*16+n.

__global__ __launch_bounds__(256) void scan_part1(
    const float* __restrict__ xr, const float* __restrict__ xs,
    const float* __restrict__ xdbl, const float* __restrict__ A_log,
    float* __restrict__ P, float* __restrict__ S, int CL)
{
    const int t = blockIdx.x * 256 + threadIdx.x;
    const int d = t % D_INNER;
    const int cb = t / D_INNER;
    const int b = cb % BATCH;
    const int c = cb / BATCH;
    const int l0 = c * CL;

    float Ac[16];
#pragma unroll
    for (int q = 0; q < 4; ++q) {
        float4 v = ((const float4*)(A_log + d * 16))[q];
        Ac[q*4+0] = -__expf(v.x); Ac[q*4+1] = -__expf(v.y);
        Ac[q*4+2] = -__expf(v.z); Ac[q*4+3] = -__expf(v.w);
    }
    float h[16];
#pragma unroll
    for (int n = 0; n < 16; ++n) h[n] = 0.f;
    float sdt = 0.f;

    const float* dptr = xr   + ((size_t)b * SEQ + l0) * (2 * D_INNER) + d;
    const float* xptr = xs   + ((size_t)b * SEQ + l0) * D_INNER + d;
    const float* brow = xdbl + ((size_t)b * SEQ + l0) * 80 + DT_RANK;

    for (int l = 0; l < CL; ++l) {
        float dt = *dptr;
        float xt = *xptr;
        float cc = dt * xt;
        float Bv[16];
#pragma unroll
        for (int q = 0; q < 4; ++q) {
            float4 v = ((const float4*)brow)[q];
            Bv[q*4+0]=v.x; Bv[q*4+1]=v.y; Bv[q*4+2]=v.z; Bv[q*4+3]=v.w;
        }
#pragma unroll
        for (int n = 0; n < 16; ++n)
            h[n] = fmaf(__expf(Ac[n] * dt), h[n], cc * Bv[n]);
        sdt += dt;
        dptr += 2 * D_INNER; xptr += D_INNER; brow += 80;
    }
#pragma unroll
    for (int n = 0; n < 16; ++n) {
        P[(size_t)t * 16 + n] = __expf(Ac[n] * sdt);
        S[(size_t)t * 16 + n] = h[n];
    }
}

__global__ __launch_bounds__(256) void scan_combine(
    const float* __restrict__ P, const float* __restrict__ S,
    float* __restrict__ Hin, int NC)
{
    const int j = blockIdx.x * 256 + threadIdx.x;   // < NSTATE_TOT
    float h = 0.f;
    for (int c = 0; c < NC; ++c) {
        size_t idx = (size_t)c * NSTATE_TOT + j;
        Hin[idx] = h;
        h = fmaf(P[idx], h, S[idx]);
    }
}

__global__ __launch_bounds__(256) void scan_part2(
    const float* __restrict__ xr, const float* __restrict__ xdbl,
    const float* __restrict__ A_log, const float* __restrict__ Dvec,
    const float* __restrict__ Hin, float* __restrict__ xs_y, int CL)
{
    const int t = blockIdx.x * 256 + threadIdx.x;
    const int d = t % D_INNER;
    const int cb = t / D_INNER;
    const int b = cb % BATCH;
    const int c = cb / BATCH;
    const int l0 = c * CL;

    float Ac[16];
#pragma unroll
    for (int q = 0; q < 4; ++q) {
        float4 v = ((const float4*)(A_log + d * 16))[q];
        Ac[q*4+0] = -__expf(v.x); Ac[q*4+1] = -__expf(v.y);
        Ac[q*4+2] = -__expf(v.z); Ac[q*4+3] = -__expf(v.w);
    }
    const float Dd = Dvec[d];
    float h[16];
    if (Hin) {
#pragma unroll
        for (int q = 0; q < 4; ++q) {
            float4 v = ((const float4*)(Hin + (size_t)t * 16))[q];
            h[q*4+0]=v.x; h[q*4+1]=v.y; h[q*4+2]=v.z; h[q*4+3]=v.w;
        }
    } else {
#pragma unroll
        for (int n = 0; n < 16; ++n) h[n] = 0.f;
    }

    const float* dptr = xr   + ((size_t)b * SEQ + l0) * (2 * D_INNER) + d;
    const float* rptr = dptr + D_INNER;
    const float* brow = xdbl + ((size_t)b * SEQ + l0) * 80 + DT_RANK;
    float*       xptr = xs_y + ((size_t)b * SEQ + l0) * D_INNER + d;

    for (int l = 0; l < CL; ++l) {
        float dt = *dptr;
        float xt = *xptr;
        float res = *rptr;
        float cc = dt * xt;
        float Bv[16], Cv[16];
#pragma unroll
        for (int q = 0; q < 4; ++q) {
            float4 v = ((const float4*)brow)[q];
            Bv[q*4+0]=v.x; Bv[q*4+1]=v.y; Bv[q*4+2]=v.z; Bv[q*4+3]=v.w;
            float4 w = ((const float4*)brow)[q + 4];
            Cv[q*4+0]=w.x; Cv[q*4+1]=w.y; Cv[q*4+2]=w.z; Cv[q*4+3]=w.w;
        }
#pragma unroll
        for (int n = 0; n < 16; ++n)
            h[n] = fmaf(__expf(Ac[n] * dt), h[n], cc * Bv[n]);
        float y0 = 0.f, y1 = 0.f, y2 = 0.f, y3 = 0.f;
#pragma unroll
        for (int n = 0; n < 4; ++n) {
            y0 = fmaf(h[n],      Cv[n],      y0);
            y1 = fmaf(h[n + 4],  Cv[n + 4],  y1);
            y2 = fmaf(h[n + 8],  Cv[n + 8],  y2);
            y3 = fmaf(h[n + 12], Cv[n + 12], y3);
        }
        float y = (y0 + y1) + (y2 + y3);
        *xptr = (y + xt * Dd) * siluf(res);
        dptr += 2 * D_INNER; rptr += 2 * D_INNER; brow += 80; xptr += D_INNER;
    }
}

extern "C" void kernel_launch(void* const* d_in, const int* in_sizes, int n_in,
                              void* d_out, int out_size, void* d_ws, size_t ws_size,
                              hipStream_t stream) {
    const float* x      = (const float*)d_in[0];
    const float* W_in   = (const float*)d_in[1];
    const float* W_conv = (const float*)d_in[2];
    const float* b_conv = (const float*)d_in[3];
    const float* W_xproj= (const float*)d_in[4];
    const float* W_dt   = (const float*)d_in[5];
    const float* b_dt   = (const float*)d_in[6];
    const float* A_log  = (const float*)d_in[7];
    const float* Dv     = (const float*)d_in[8];
    const float* W_out  = (const float*)d_in[9];
    float* out = (float*)d_out;

    float* ws   = (float*)d_ws;
    float* xr   = ws;                               // BL * 3072
    float* xs   = xr + (size_t)BL * 3072;           // BL * 1536
    float* xdbl = xs + (size_t)BL * 1536;           // BL * 80
    float* scr  = xdbl + (size_t)BL * 80;           // scan scratch: P, S, Hin

    size_t fixed_bytes = ((size_t)BL * 3072 + (size_t)BL * 1536 + (size_t)BL * 80) * 4;
    int NC = 0;
    for (int cand = 64; cand >= 2; cand >>= 1) {
        size_t need = fixed_bytes + 3ull * cand * NSTATE_TOT * 4;
        if (need <= ws_size) { NC = cand; break; }
    }

    dim3 blk(256);

    // 1) in_proj: xr = x @ W_in^T           (4096 x 3072, K=768)
    gemm_mfma<128, 128, 64, 64, 0><<<dim3(BL / 128, 3072 / 128), blk, 0, stream>>>(
        x, W_in, nullptr, xr, BL, 2 * D_INNER, D_MODEL, D_MODEL, D_MODEL, 2 * D_INNER);

    // 2) causal depthwise conv + bias + SiLU -> xs
    conv_silu_kernel<<<dim3((BL * D_INNER) / 256), blk, 0, stream>>>(xr, W_conv, b_conv, xs);

    // 3) x_proj: xdbl = xs @ W_xproj^T      (4096 x 80, K=1536)
    gemm_mfma<64, 80, 16, 80, 0><<<dim3(BL / 64, 1), blk, 0, stream>>>(
        xs, W_xproj, nullptr, xdbl, BL, DT_RANK + 2 * D_STATE, D_INNER, D_INNER, D_INNER, 80);

    // 4) delta = softplus(xdbl[:, :48] @ W_dt^T + b_dt) -> xr cols [0,1536), ldc=3072
    gemm_mfma<128, 128, 64, 64, 1><<<dim3(BL / 128, D_INNER / 128), blk, 0, stream>>>(
        xdbl, W_dt, b_dt, xr, BL, D_INNER, DT_RANK, 80, DT_RANK, 2 * D_INNER);

    // 5) chunked selective scan + D-skip + gate, in-place on xs
    if (NC >= 2) {
        const int CL = SEQ / NC;
        float* P   = scr;
        float* S   = P + (size_t)NC * NSTATE_TOT;
        float* Hin = S + (size_t)NC * NSTATE_TOT;
        scan_part1<<<dim3(NC * BATCH * D_INNER / 256), blk, 0, stream>>>(
            xr, xs, xdbl, A_log, P, S, CL);
        scan_combine<<<dim3(NSTATE_TOT / 256), blk, 0, stream>>>(P, S, Hin, NC);
        scan_part2<<<dim3(NC * BATCH * D_INNER / 256), blk, 0, stream>>>(
            xr, xdbl, A_log, Dv, Hin, xs, CL);
    } else {
        scan_part2<<<dim3(BATCH * D_INNER / 256), blk, 0, stream>>>(
            xr, xdbl, A_log, Dv, nullptr, xs, SEQ);
    }

    // 6) out_proj: out = y_gated @ W_out^T  (4096 x 768, K=1536)
    gemm_mfma<128, 128, 64, 64, 0><<<dim3(BL / 128, D_MODEL / 128), blk, 0, stream>>>(
        xs, W_out, nullptr, out, BL, D_MODEL, D_INNER, D_INNER, D_INNER, D_MODEL);
}